// Round 4
// baseline (375.026 us; speedup 1.0000x reference)
//
#include <hip/hip_runtime.h>
#include <hip/hip_cooperative_groups.h>

// SparseToDense: scatter features [N,32] into dense [B=4, C=32, D=64, H=64, W=64].
// flat_idx (int32 on device) indexes B*D*H*W sites; output is NCDHW. DHW = 2^18.
//
// R10: cooperative fusion REDONE without the R8 mistake.
//   R8 post-mortem (resolved): __launch_bounds__(256,8) -> VGPR_Count=24 ->
//   the 16-float acc + 16 in-flight load floats SPILLED to scratch. That one
//   mistake explains the 362us, the 5% HBM, and the 153MB FETCH (spill
//   traffic). The fusion structure itself was never refuted.
//   R9b post-mortem: LDS-transposed 512B-contiguous NT stores were NEUTRAL
//   (203.5 -> 201.8) -> write-stream contiguity below 512B was not the gather
//   limiter. Kept anyway (never worse, fewer store instrs).
// R10 = one cooperative kernel: init -> grid.sync -> build -> grid.sync ->
//   gather(+LDS epilogue). Natural register allocation (NO min-waves bound).
//   Removes 2 launch gaps + init dispatch, and -- critically -- produces a
//   single ~90-105us dispatch that outranks the ~80us harness poison fills in
//   the rocprof top-5, giving first counter visibility into the pipeline.
// Kept: cached loads for feats/head/next (R6: NT loads regress); NT stores
//   (134MB stream must not evict chain data from L2); 2 threads/site;
//   4-wide load batching in the chain walk (ILP).
// Budget model: fill 80 (harness, fixed) + out-poison ~21 + mine ~90-100.

#define DHW_LOG2 18
#define DHW (1 << DHW_LOG2)
#define C_CH 32
#define N_SITES_TOTAL (4 * DHW)   // B=4 -> 1048576 sites
#define SITES_PER_BLOCK 128       // per tile: 256 threads, 2 threads/site
#define N_TILES (N_SITES_TOTAL / SITES_PER_BLOCK)   // 8192
#define LDS_PAD 132               // 132%32=4 -> 2-way bank aliasing (free); 528B rows stay 16B-aligned

typedef float floatx4 __attribute__((ext_vector_type(4)));

namespace cg = cooperative_groups;

__global__ __launch_bounds__(256) void fused_kernel(
    const float* __restrict__ feats,
    const int* __restrict__ flat_idx,
    int* __restrict__ head,
    int* __restrict__ next,
    float* __restrict__ out,
    int n_active)
{
    cg::grid_group grid = cg::this_grid();
    __shared__ __align__(16) float lds[C_CH][LDS_PAD];

    const int t    = threadIdx.x;
    const int tid0 = blockIdx.x * blockDim.x + t;
    const int nthr = gridDim.x * blockDim.x;

    // ---- Phase A: head[:] = -1 (8B stores, grid-stride) ----
    int2* head2 = (int2*)head;
    for (int i = tid0; i < N_SITES_TOTAL / 2; i += nthr)
        head2[i] = make_int2(-1, -1);

    grid.sync();

    // ---- Phase B: build per-site chains (device-scope atomicExch, 4MB head) ----
    for (int i = tid0; i < n_active; i += nthr) {
        int s = flat_idx[i];
        int prev = atomicExch(&head[s], i);
        next[i] = prev;
    }

    grid.sync();

    // ---- Phase C: gather, tile-strided. Each tile = 128 consecutive sites.
    // 2 threads/site: thread (sl,h) owns channels h*16..h*16+15 of site sl. ----
    const int sl = t >> 1;
    const int h  = t & 1;

    for (int tile = blockIdx.x; tile < N_TILES; tile += gridDim.x) {
        const int S0 = tile * SITES_PER_BLOCK;
        const int S  = S0 + sl;

        floatx4 a0 = (floatx4)0.f, a1 = (floatx4)0.f, a2 = (floatx4)0.f, a3 = (floatx4)0.f;

        int p = head[S];          // pair lanes broadcast; L2-resident 4MB
        while (p != -1) {
            const floatx4* row = (const floatx4*)(feats + ((size_t)p * C_CH + h * 16));
            int pn = next[p];             // issue next-hop early
            floatx4 f0 = row[0];          // cached: 1 line fill + L1 hits per 64B half
            floatx4 f1 = row[1];
            floatx4 f2 = row[2];
            floatx4 f3 = row[3];
            a0 += f0; a1 += f1; a2 += f2; a3 += f3;
            p = pn;
        }

        // Transpose through LDS: lds[c][site_local]; 2-way bank aliasing = free.
        float acc[16] = {
            a0.x, a0.y, a0.z, a0.w,  a1.x, a1.y, a1.z, a1.w,
            a2.x, a2.y, a2.z, a2.w,  a3.x, a3.y, a3.z, a3.w };
        #pragma unroll
        for (int j = 0; j < 16; ++j)
            lds[h * 16 + j][sl] = acc[j];

        __syncthreads();

        // Stream out: per half-wave, 32 lanes x float4 = 512B contiguous per channel.
        const int b   = S0 >> DHW_LOG2;
        const int sp0 = S0 & (DHW - 1);
        #pragma unroll
        for (int it = 0; it < 4; ++it) {
            int q  = it * 256 + t;
            int c  = q >> 5;      // 0..31
            int i4 = q & 31;      // float4 index within this tile's channel run
            floatx4 v = *reinterpret_cast<const floatx4*>(&lds[c][i4 * 4]);
            floatx4* o = reinterpret_cast<floatx4*>(
                out + (((size_t)(b * C_CH + c)) << DHW_LOG2) + sp0 + i4 * 4);
            __builtin_nontemporal_store(v, o);
        }

        __syncthreads();          // LDS reused next tile
    }
}

// ---- non-cooperative 3-kernel path (R9b behavior) as fallback ----

__global__ __launch_bounds__(256) void init_head_kernel(int* __restrict__ head, int n)
{
    int t = blockIdx.x * blockDim.x + threadIdx.x;
    if (t < n) head[t] = -1;
}

__global__ __launch_bounds__(256) void build_chains_kernel(
    const int* __restrict__ flat_idx,
    int* __restrict__ head,
    int* __restrict__ next,
    int n_active)
{
    int i = blockIdx.x * blockDim.x + threadIdx.x;
    if (i >= n_active) return;
    int s = flat_idx[i];
    int prev = atomicExch(&head[s], i);
    next[i] = prev;
}

__global__ __launch_bounds__(256) void gather_kernel(
    const float* __restrict__ feats,
    const int* __restrict__ head,
    const int* __restrict__ next,
    float* __restrict__ out)
{
    __shared__ __align__(16) float lds[C_CH][LDS_PAD];

    const int t  = threadIdx.x;
    const int sl = t >> 1;
    const int h  = t & 1;
    const int S0 = blockIdx.x * SITES_PER_BLOCK;
    const int S  = S0 + sl;

    floatx4 a0 = (floatx4)0.f, a1 = (floatx4)0.f, a2 = (floatx4)0.f, a3 = (floatx4)0.f;

    int p = head[S];
    while (p != -1) {
        const floatx4* row = (const floatx4*)(feats + ((size_t)p * C_CH + h * 16));
        int pn = next[p];
        floatx4 f0 = row[0];
        floatx4 f1 = row[1];
        floatx4 f2 = row[2];
        floatx4 f3 = row[3];
        a0 += f0; a1 += f1; a2 += f2; a3 += f3;
        p = pn;
    }

    float acc[16] = {
        a0.x, a0.y, a0.z, a0.w,  a1.x, a1.y, a1.z, a1.w,
        a2.x, a2.y, a2.z, a2.w,  a3.x, a3.y, a3.z, a3.w };
    #pragma unroll
    for (int j = 0; j < 16; ++j)
        lds[h * 16 + j][sl] = acc[j];

    __syncthreads();

    const int b   = S0 >> DHW_LOG2;
    const int sp0 = S0 & (DHW - 1);
    #pragma unroll
    for (int it = 0; it < 4; ++it) {
        int q  = it * 256 + t;
        int c  = q >> 5;
        int i4 = q & 31;
        floatx4 v = *reinterpret_cast<const floatx4*>(&lds[c][i4 * 4]);
        floatx4* o = reinterpret_cast<floatx4*>(
            out + (((size_t)(b * C_CH + c)) << DHW_LOG2) + sp0 + i4 * 4);
        __builtin_nontemporal_store(v, o);
    }
}

// ---- fallback (R3 behavior) if workspace is too small ----
__global__ __launch_bounds__(256) void zero_kernel(float4* __restrict__ out, int n4)
{
    int t = blockIdx.x * blockDim.x + threadIdx.x;
    if (t < n4) out[t] = make_float4(0.f, 0.f, 0.f, 0.f);
}

__global__ __launch_bounds__(256) void scatter_atomic_kernel(
    const float* __restrict__ feats,
    const int* __restrict__ flat_idx,
    float* __restrict__ out,
    int n_active)
{
    int t = blockIdx.x * blockDim.x + threadIdx.x;
    int i = t >> 5, c = t & 31;
    if (i >= n_active) return;
    int s = flat_idx[i];
    atomicAdd(&out[(((size_t)(s >> DHW_LOG2) * C_CH + c) << DHW_LOG2) + (s & (DHW - 1))],
              feats[(size_t)i * C_CH + c]);
}

extern "C" void kernel_launch(void* const* d_in, const int* in_sizes, int n_in,
                              void* d_out, int out_size, void* d_ws, size_t ws_size,
                              hipStream_t stream) {
    const float* feats = (const float*)d_in[0];
    const int*   idx   = (const int*)d_in[1];
    float*       out   = (float*)d_out;
    int n_active = in_sizes[1];   // 400000

    size_t head_bytes = (size_t)N_SITES_TOTAL * sizeof(int);      // 4 MB
    size_t next_bytes = (size_t)n_active * sizeof(int);           // 1.6 MB

    if (ws_size >= head_bytes + next_bytes) {
        int* head = (int*)d_ws;
        int* next = (int*)((char*)d_ws + head_bytes);

        // Cooperative grid must be fully co-resident; query real occupancy
        // (natural VGPR count this time -- no min-waves strangling).
        int maxB = 0;
        hipError_t qe = hipOccupancyMaxActiveBlocksPerMultiprocessor(
            &maxB, fused_kernel, 256, 0);
        int nblocks = 0;
        if (qe == hipSuccess && maxB > 0) {
            nblocks = maxB * 256;               // 256 CUs on gfx950
            if (nblocks > N_TILES) nblocks = N_TILES;
        }

        hipError_t le = hipErrorUnknown;
        if (nblocks > 0) {
            void* args[] = { (void*)&feats, (void*)&idx, (void*)&head,
                             (void*)&next, (void*)&out, (void*)&n_active };
            le = hipLaunchCooperativeKernel(
                fused_kernel, dim3(nblocks), dim3(256), args, 0, stream);
        }

        if (le != hipSuccess) {
            // Fallback: proven R9b 3-kernel path.
            init_head_kernel<<<(N_SITES_TOTAL + 255) / 256, 256, 0, stream>>>(head, N_SITES_TOTAL);
            build_chains_kernel<<<(n_active + 255) / 256, 256, 0, stream>>>(idx, head, next, n_active);
            gather_kernel<<<N_TILES, 256, 0, stream>>>(feats, head, next, out);
        }
    } else {
        // fallback: R3 atomic path
        int n4 = out_size >> 2;
        zero_kernel<<<(n4 + 255) / 256, 256, 0, stream>>>((float4*)out, n4);
        int total = n_active * C_CH;
        scatter_atomic_kernel<<<(total + 255) / 256, 256, 0, stream>>>(feats, idx, out, n_active);
    }
}

// Round 5
// 228.228 us; speedup vs baseline: 1.6432x; 1.6432x over previous
//
#include <hip/hip_runtime.h>

// SparseToDense: scatter features [N,32] into dense [B=4, C=32, D=64, H=64, W=64].
// flat_idx (int32 on device) indexes B*D*H*W sites; output is NCDHW. DHW = 2^18.
//
// R11: kill the pointer chase. Chains -> fixed-capacity per-site BUCKETS.
//   R8/R10 post-mortem: cooperative fusion is catastrophic twice (362/354us)
//   with different VGPR profiles -> structure, not regalloc. ABANDONED.
//   But R10's counters (first real visibility): VALUBusy 1.5%, HBM 6.7%,
//   Occupancy 92% -> the hot phase is pure LATENCY serialization. The only
//   serially-dependent structure is the chain walk head->next->next (each hop
//   a full L3/HBM round trip, wave stalled on worst lane).
//   R11: build writes bucket[site*8 + pos] = i (pos = atomicAdd(count[site]))
//   -- same cost as chain build -- and gather issues all <=8 feats-row loads
//   INDEPENDENTLY (depth 2: seq count/bucket read -> random feats reads).
//   Overflow (pos>=8, ~never for Poisson(0.4) data) falls back to a chain,
//   so the kernel is correct for any input.
// Kept: R9b LDS-transpose epilogue + NT float4 stores (neutral but fewer
//   instrs; NT keeps the 134MB stream from evicting L2/L3-resident data);
//   cached loads (R6: NT loads regress); 2 threads/site (h-split of the
//   128B row); plain __launch_bounds__(256), 3 plain dispatches.
// Budget model: fills ~101 (harness) + init ~3 + fill ~20 + gather ~40-50.

#define DHW_LOG2 18
#define DHW (1 << DHW_LOG2)
#define C_CH 32
#define N_SITES_TOTAL (4 * DHW)   // B=4 -> 1048576 sites
#define SITES_PER_BLOCK 128       // 256 threads, 2 threads/site
#define N_TILES (N_SITES_TOTAL / SITES_PER_BLOCK)   // 8192
#define LDS_PAD 132               // 132%32=4 -> 2-way bank aliasing (free); rows 16B-aligned
#define CAP 8                     // bucket slots/site; 32B/site -> int4 pair, seq-coalesced

typedef float floatx4 __attribute__((ext_vector_type(4)));

__global__ __launch_bounds__(256) void init_kernel(int* __restrict__ count,
                                                   int* __restrict__ ovf_head)
{
    int t = blockIdx.x * blockDim.x + threadIdx.x;
    if (t < N_SITES_TOTAL / 2) {
        ((int2*)count)[t]    = make_int2(0, 0);
        ((int2*)ovf_head)[t] = make_int2(-1, -1);
    }
}

__global__ __launch_bounds__(256) void fill_buckets_kernel(
    const int* __restrict__ flat_idx,
    int* __restrict__ count,
    int* __restrict__ bucket,
    int* __restrict__ ovf_head,
    int* __restrict__ ovf_next,
    int n_active)
{
    int i = blockIdx.x * blockDim.x + threadIdx.x;
    if (i >= n_active) return;
    int s = flat_idx[i];
    int pos = atomicAdd(&count[s], 1);          // device-scope, 4MB array (~19us)
    if (pos < CAP) {
        bucket[(size_t)s * CAP + pos] = i;      // scattered 4B store (like old next[])
    } else {                                    // ~never on random data; correctness path
        int prev = atomicExch(&ovf_head[s], i);
        ovf_next[i] = prev;
    }
}

__global__ __launch_bounds__(256) void gather_kernel(
    const float* __restrict__ feats,
    const int* __restrict__ count,
    const int* __restrict__ bucket,
    const int* __restrict__ ovf_head,
    const int* __restrict__ ovf_next,
    float* __restrict__ out)
{
    __shared__ __align__(16) float lds[C_CH][LDS_PAD];

    const int t  = threadIdx.x;
    const int sl = t >> 1;        // site within block (lane pairs share a site)
    const int h  = t & 1;         // channel half: channels h*16 .. h*16+15
    const int S0 = blockIdx.x * SITES_PER_BLOCK;
    const int S  = S0 + sl;

    // Two independent sequential streams, issued together (no dependence):
    int c = count[S];
    const int4* bkt = (const int4*)(bucket + (size_t)S * CAP);
    int4 b0 = bkt[0];             // 32B = the site's full slot line, coalesced in S
    int4 b1 = bkt[1];

    floatx4 a0 = (floatx4)0.f, a1 = (floatx4)0.f, a2 = (floatx4)0.f, a3 = (floatx4)0.f;

    // Up to 8 INDEPENDENT feats-row loads (exec-masked; k is compile-time ->
    // no scratch, rule #20). Typical wave executes 2-3 of the 8 segments
    // (s_cbranch_execz skips the rest).
    const int rows[CAP] = { b0.x, b0.y, b0.z, b0.w, b1.x, b1.y, b1.z, b1.w };
    #pragma unroll
    for (int k = 0; k < CAP; ++k) {
        if (k < c) {
            const floatx4* row = (const floatx4*)(feats + ((size_t)rows[k] * C_CH + h * 16));
            floatx4 f0 = row[0];
            floatx4 f1 = row[1];
            floatx4 f2 = row[2];
            floatx4 f3 = row[3];
            a0 += f0; a1 += f1; a2 += f2; a3 += f3;
        }
    }

    if (c > CAP) {                // cold overflow path: old chain walk
        int p = ovf_head[S];
        while (p != -1) {
            const floatx4* row = (const floatx4*)(feats + ((size_t)p * C_CH + h * 16));
            int pn = ovf_next[p];
            floatx4 f0 = row[0];
            floatx4 f1 = row[1];
            floatx4 f2 = row[2];
            floatx4 f3 = row[3];
            a0 += f0; a1 += f1; a2 += f2; a3 += f3;
            p = pn;
        }
    }

    // Transpose through LDS: lds[ch][site_local]; 2-way bank aliasing = free.
    float acc[16] = {
        a0.x, a0.y, a0.z, a0.w,  a1.x, a1.y, a1.z, a1.w,
        a2.x, a2.y, a2.z, a2.w,  a3.x, a3.y, a3.z, a3.w };
    #pragma unroll
    for (int j = 0; j < 16; ++j)
        lds[h * 16 + j][sl] = acc[j];

    __syncthreads();

    // Stream out: 32 lanes x float4 = 512B contiguous per channel per instr.
    const int b   = S0 >> DHW_LOG2;
    const int sp0 = S0 & (DHW - 1);
    #pragma unroll
    for (int it = 0; it < 4; ++it) {
        int q  = it * 256 + t;
        int cc = q >> 5;          // 0..31
        int i4 = q & 31;          // float4 index within this block's channel run
        floatx4 v = *reinterpret_cast<const floatx4*>(&lds[cc][i4 * 4]);
        floatx4* o = reinterpret_cast<floatx4*>(
            out + (((size_t)(b * C_CH + cc)) << DHW_LOG2) + sp0 + i4 * 4);
        __builtin_nontemporal_store(v, o);
    }
}

// ---- fallback (R3 behavior) if workspace is too small ----
__global__ __launch_bounds__(256) void zero_kernel(float4* __restrict__ out, int n4)
{
    int t = blockIdx.x * blockDim.x + threadIdx.x;
    if (t < n4) out[t] = make_float4(0.f, 0.f, 0.f, 0.f);
}

__global__ __launch_bounds__(256) void scatter_atomic_kernel(
    const float* __restrict__ feats,
    const int* __restrict__ flat_idx,
    float* __restrict__ out,
    int n_active)
{
    int t = blockIdx.x * blockDim.x + threadIdx.x;
    int i = t >> 5, c = t & 31;
    if (i >= n_active) return;
    int s = flat_idx[i];
    atomicAdd(&out[(((size_t)(s >> DHW_LOG2) * C_CH + c) << DHW_LOG2) + (s & (DHW - 1))],
              feats[(size_t)i * C_CH + c]);
}

extern "C" void kernel_launch(void* const* d_in, const int* in_sizes, int n_in,
                              void* d_out, int out_size, void* d_ws, size_t ws_size,
                              hipStream_t stream) {
    const float* feats = (const float*)d_in[0];
    const int*   idx   = (const int*)d_in[1];
    float*       out   = (float*)d_out;
    int n_active = in_sizes[1];   // 400000

    // ws layout: count 4MB | ovf_head 4MB | ovf_next 1.6MB (padded to 8MB) | bucket 32MB
    size_t count_bytes = (size_t)N_SITES_TOTAL * sizeof(int);        // 4 MB
    size_t head_bytes  = (size_t)N_SITES_TOTAL * sizeof(int);        // 4 MB
    size_t next_bytes  = ((size_t)n_active * sizeof(int) + 0xFFFFF) & ~(size_t)0xFFFFF;
    size_t bucket_off  = count_bytes + head_bytes + next_bytes;
    size_t bucket_bytes = (size_t)N_SITES_TOTAL * CAP * sizeof(int); // 32 MB

    if (ws_size >= bucket_off + bucket_bytes) {
        int* count    = (int*)d_ws;
        int* ovf_head = (int*)((char*)d_ws + count_bytes);
        int* ovf_next = (int*)((char*)d_ws + count_bytes + head_bytes);
        int* bucket   = (int*)((char*)d_ws + bucket_off);

        init_kernel<<<(N_SITES_TOTAL / 2 + 255) / 256, 256, 0, stream>>>(count, ovf_head);
        fill_buckets_kernel<<<(n_active + 255) / 256, 256, 0, stream>>>(
            idx, count, bucket, ovf_head, ovf_next, n_active);
        // 8192 blocks x 256 threads; each block owns 128 consecutive sites.
        gather_kernel<<<N_TILES, 256, 0, stream>>>(
            feats, count, bucket, ovf_head, ovf_next, out);
    } else {
        // fallback: R3 atomic path
        int n4 = out_size >> 2;
        zero_kernel<<<(n4 + 255) / 256, 256, 0, stream>>>((float4*)out, n4);
        int total = n_active * C_CH;
        scatter_atomic_kernel<<<(total + 255) / 256, 256, 0, stream>>>(feats, idx, out, n_active);
    }
}

// Round 6
// 201.458 us; speedup vs baseline: 1.8616x; 1.1329x over previous
//
#include <hip/hip_runtime.h>

// SparseToDense: scatter features [N,32] into dense [B=4, C=32, D=64, H=64, W=64].
// flat_idx (int32 on device) indexes B*D*H*W sites; output is NCDHW. DHW = 2^18.
//
// R12: chain pipeline (R9b) + L3-PREFETCH of feats fused into the build phase.
//   Evidence so far: store contiguity neutral (R9b), chase removal neutral
//   (R11, clock-normalized), VALU 1.5% / occupancy 92% (R10) -> gather's
//   ~2x-over-floor cost is none of {stores, chase depth, VALU, occupancy}.
//   Remaining suspect: the 512MB per-iteration ws poison fill evicts L2+L3,
//   so gather's 400k random 128B feats reads hit HBM, wrecking DRAM page
//   locality against the 134MB sequential write stream (2.9 TB/s effective
//   vs 6.7 pure-write).
//   R12: sequential sweep of feats (51MB, ~8-10us) runs in EXTRA blocks of
//   the build dispatch (build is atomic-fabric-bound, ~19us, ~3MB traffic ->
//   BW is free). L3 is memory-side: the sweep populates it; build's ~6MB of
//   writes can't evict 51MB from 256MB. Gather then reads feats from L3 and
//   DRAM sees a near-pure write stream.
// Kept: R9b LDS-transpose epilogue + NT float4 stores; cached loads (R6: NT
//   loads regress); 2 threads/site; chains (leaner than R11 buckets).
// Budget model: fills ~101 (harness, fixed) + init ~2 + build/prefetch ~20
//   + gather ~35-45.

#define DHW_LOG2 18
#define DHW (1 << DHW_LOG2)
#define C_CH 32
#define N_SITES_TOTAL (4 * DHW)   // B=4 -> 1048576 sites
#define SITES_PER_BLOCK 128       // 256 threads, 2 threads/site
#define N_TILES (N_SITES_TOTAL / SITES_PER_BLOCK)   // 8192
#define LDS_PAD 132               // 132%32=4 -> 2-way bank aliasing (free); rows 16B-aligned
#define PF_BLOCKS 768             // prefetch sweep blocks fused into build dispatch

typedef float floatx4 __attribute__((ext_vector_type(4)));

__global__ __launch_bounds__(256) void init_head_kernel(int* __restrict__ head, int n)
{
    int t = blockIdx.x * blockDim.x + threadIdx.x;
    if (t < n) head[t] = -1;
}

// Build chains in blocks [0, build_blocks); sweep feats into L3 in the rest.
__global__ __launch_bounds__(256) void build_chains_prefetch_kernel(
    const int* __restrict__ flat_idx,
    int* __restrict__ head,
    int* __restrict__ next,
    const floatx4* __restrict__ feats4,
    int n_active,
    int n4,                // n_active * 8  (feats floats / 4)
    int build_blocks)
{
    if ((int)blockIdx.x < build_blocks) {
        int i = blockIdx.x * blockDim.x + threadIdx.x;
        if (i >= n_active) return;
        int s = flat_idx[i];
        int prev = atomicExch(&head[s], i);   // device-scope int atomic, 4 MB array
        next[i] = prev;
    } else {
        // Sequential sweep: populate memory-side L3 with feats (51 MB).
        int t = (blockIdx.x - build_blocks) * blockDim.x + threadIdx.x;
        const int nthr = PF_BLOCKS * 256;
        floatx4 acc = (floatx4)0.f;
        for (int i = t; i < n4; i += nthr)
            acc += feats4[i];                 // cached load -> fills L2/L3
        // Keep the loads alive without any visible side effect (rule #17).
        asm volatile("" :: "v"(acc.x), "v"(acc.y), "v"(acc.z), "v"(acc.w));
    }
}

__global__ __launch_bounds__(256) void gather_kernel(
    const float* __restrict__ feats,
    const int* __restrict__ head,
    const int* __restrict__ next,
    float* __restrict__ out)
{
    __shared__ __align__(16) float lds[C_CH][LDS_PAD];

    const int t  = threadIdx.x;
    const int sl = t >> 1;        // site within block (lane pairs share a site)
    const int h  = t & 1;         // channel half: channels h*16 .. h*16+15
    const int S0 = blockIdx.x * SITES_PER_BLOCK;
    const int S  = S0 + sl;

    floatx4 a0 = (floatx4)0.f, a1 = (floatx4)0.f, a2 = (floatx4)0.f, a3 = (floatx4)0.f;

    int p = head[S];              // coalesced in S; pair lanes broadcast
    while (p != -1) {
        const floatx4* row = (const floatx4*)(feats + ((size_t)p * C_CH + h * 16));
        int pn = next[p];                 // issue next-hop early
        floatx4 f0 = row[0];              // L3-resident after prefetch sweep
        floatx4 f1 = row[1];
        floatx4 f2 = row[2];
        floatx4 f3 = row[3];
        a0 += f0; a1 += f1; a2 += f2; a3 += f3;
        p = pn;
    }

    // Transpose through LDS: lds[c][site_local]; 2-way bank aliasing = free.
    float acc[16] = {
        a0.x, a0.y, a0.z, a0.w,  a1.x, a1.y, a1.z, a1.w,
        a2.x, a2.y, a2.z, a2.w,  a3.x, a3.y, a3.z, a3.w };
    #pragma unroll
    for (int j = 0; j < 16; ++j)
        lds[h * 16 + j][sl] = acc[j];

    __syncthreads();

    // Stream out: 32 lanes x float4 = 512B contiguous per channel per instr.
    const int b   = S0 >> DHW_LOG2;
    const int sp0 = S0 & (DHW - 1);
    #pragma unroll
    for (int it = 0; it < 4; ++it) {
        int q  = it * 256 + t;
        int c  = q >> 5;          // 0..31
        int i4 = q & 31;          // float4 index within this block's channel run
        floatx4 v = *reinterpret_cast<const floatx4*>(&lds[c][i4 * 4]);
        floatx4* o = reinterpret_cast<floatx4*>(
            out + (((size_t)(b * C_CH + c)) << DHW_LOG2) + sp0 + i4 * 4);
        __builtin_nontemporal_store(v, o);
    }
}

// ---- fallback (R3 behavior) if workspace is too small ----
__global__ __launch_bounds__(256) void zero_kernel(float4* __restrict__ out, int n4)
{
    int t = blockIdx.x * blockDim.x + threadIdx.x;
    if (t < n4) out[t] = make_float4(0.f, 0.f, 0.f, 0.f);
}

__global__ __launch_bounds__(256) void scatter_atomic_kernel(
    const float* __restrict__ feats,
    const int* __restrict__ flat_idx,
    float* __restrict__ out,
    int n_active)
{
    int t = blockIdx.x * blockDim.x + threadIdx.x;
    int i = t >> 5, c = t & 31;
    if (i >= n_active) return;
    int s = flat_idx[i];
    atomicAdd(&out[(((size_t)(s >> DHW_LOG2) * C_CH + c) << DHW_LOG2) + (s & (DHW - 1))],
              feats[(size_t)i * C_CH + c]);
}

extern "C" void kernel_launch(void* const* d_in, const int* in_sizes, int n_in,
                              void* d_out, int out_size, void* d_ws, size_t ws_size,
                              hipStream_t stream) {
    const float* feats = (const float*)d_in[0];
    const int*   idx   = (const int*)d_in[1];
    float*       out   = (float*)d_out;
    int n_active = in_sizes[1];   // 400000

    size_t head_bytes = (size_t)N_SITES_TOTAL * sizeof(int);      // 4 MB
    size_t next_bytes = (size_t)n_active * sizeof(int);           // 1.6 MB

    if (ws_size >= head_bytes + next_bytes) {
        int* head = (int*)d_ws;
        int* next = (int*)((char*)d_ws + head_bytes);

        int build_blocks = (n_active + 255) / 256;     // 1563
        int n4 = n_active * (C_CH / 4);                // feats in float4 units

        init_head_kernel<<<(N_SITES_TOTAL + 255) / 256, 256, 0, stream>>>(head, N_SITES_TOTAL);
        build_chains_prefetch_kernel<<<build_blocks + PF_BLOCKS, 256, 0, stream>>>(
            idx, head, next, (const floatx4*)feats, n_active, n4, build_blocks);
        // 8192 blocks x 256 threads; each block owns 128 consecutive sites.
        gather_kernel<<<N_TILES, 256, 0, stream>>>(feats, head, next, out);
    } else {
        // fallback: R3 atomic path
        int n4 = out_size >> 2;
        zero_kernel<<<(n4 + 255) / 256, 256, 0, stream>>>((float4*)out, n4);
        int total = n_active * C_CH;
        scatter_atomic_kernel<<<(total + 255) / 256, 256, 0, stream>>>(feats, idx, out, n_active);
    }
}